// Round 2
// baseline (1887.540 us; speedup 1.0000x reference)
//
#include <hip/hip_runtime.h>

// ---------------------------------------------------------------------------
// TorchGRUClassifier: 2-layer GRU (B=1024, T=256, I=153, H=128) + MLP head.
// Round 2: (a) gi0 = x @ W_ih0^T hoisted into a full-chip GEMM (the only
// non-sequential 30 GFLOP); (b) recurrent kernel keeps only gh0/gi1/gh1 with
// weight B-fragments forced into VGPRs via volatile loads (round-1 counter
// showed VGPR_Count=128 -> compiler was re-loading them every step);
// (c) double-buffered h tiles -> 1 barrier/step instead of 3.
// ---------------------------------------------------------------------------

typedef __bf16 bf16x8 __attribute__((ext_vector_type(8)));
typedef float  f32x4  __attribute__((ext_vector_type(4)));
typedef unsigned int u32x4v __attribute__((ext_vector_type(4)));

#define HS 136  // LDS row stride (bf16 elems) for h tiles: 128 + 8 pad

__device__ __forceinline__ f32x4 mfma16(bf16x8 a, bf16x8 b, f32x4 c) {
    return __builtin_amdgcn_mfma_f32_16x16x32_bf16(a, b, c, 0, 0, 0);
}
__device__ __forceinline__ float sigf(float x)   { return 1.f / (1.f + __expf(-x)); }
__device__ __forceinline__ float tanhf_(float x) { return 2.f * sigf(2.f * x) - 1.f; }

// ---- prep: cast weights to bf16 (W_ih0 padded K 153->160 with zeros) ------
__global__ void prep_w_kernel(const float* __restrict__ Wih0, const float* __restrict__ Whh0,
                              const float* __restrict__ Wih1, const float* __restrict__ Whh1,
                              __bf16* __restrict__ o_ih0, __bf16* __restrict__ o_hh0,
                              __bf16* __restrict__ o_ih1, __bf16* __restrict__ o_hh1) {
    int idx = blockIdx.x * 256 + threadIdx.x;      // grid covers 384*160 = 61440
    if (idx < 384 * 160) {
        int n = idx / 160, k = idx - n * 160;
        o_ih0[idx] = (__bf16)(k < 153 ? Wih0[n * 153 + k] : 0.f);
    }
    if (idx < 384 * 128) {
        o_hh0[idx] = (__bf16)Whh0[idx];
        o_ih1[idx] = (__bf16)Wih1[idx];
        o_hh1[idx] = (__bf16)Whh1[idx];
    }
}

// ---- gi0 GEMM: [262144,153(pad160)] x [160,384] -> gi0 bf16 [262144][384] --
// row = b*256 + t (x's natural order). Casts x f32->bf16 during LDS staging.
__global__ __launch_bounds__(512, 2) void gi0_gemm_kernel(
    const float* __restrict__ x, const __bf16* __restrict__ Wih0b,
    __bf16* __restrict__ gi0)
{
    __shared__ __bf16 As[128 * 160];   // 40 KB
    const int r0  = blockIdx.x * 128;
    const int tid = threadIdx.x;
    for (int e = tid; e < 128 * 160; e += 512) {
        int r = e / 160, c = e - r * 160;
        float v = (c < 153) ? x[(size_t)(r0 + r) * 153 + c] : 0.f;
        As[e] = (__bf16)v;
    }
    __syncthreads();
    const int w = tid >> 6, lane = tid & 63, q = lane >> 4, c15 = lane & 15;

    // B-fragments for this wave's 3 col-tiles (cols 16*(w+8j)+c15), L2-hot
    bf16x8 bf[3][5];
    #pragma unroll
    for (int j = 0; j < 3; ++j) {
        int colb = 16 * (w + 8 * j) + c15;
        #pragma unroll
        for (int ks = 0; ks < 5; ++ks)
            bf[j][ks] = *(const bf16x8*)(Wih0b + colb * 160 + ks * 32 + q * 8);
    }
    f32x4 acc[8][3];
    #pragma unroll
    for (int rt = 0; rt < 8; ++rt)
        #pragma unroll
        for (int j = 0; j < 3; ++j) acc[rt][j] = (f32x4){0.f, 0.f, 0.f, 0.f};

    #pragma unroll
    for (int ks = 0; ks < 5; ++ks) {
        bf16x8 a[8];
        #pragma unroll
        for (int rt = 0; rt < 8; ++rt)
            a[rt] = *(const bf16x8*)(&As[(rt * 16 + c15) * 160 + ks * 32 + q * 8]);
        #pragma unroll
        for (int rt = 0; rt < 8; ++rt)
            #pragma unroll
            for (int j = 0; j < 3; ++j) acc[rt][j] = mfma16(a[rt], bf[j][ks], acc[rt][j]);
    }
    #pragma unroll
    for (int rt = 0; rt < 8; ++rt)
        #pragma unroll
        for (int j = 0; j < 3; ++j) {
            int col = 16 * (w + 8 * j) + c15;
            #pragma unroll
            for (int r = 0; r < 4; ++r) {
                int row = r0 + rt * 16 + q * 4 + r;
                gi0[(size_t)row * 384 + col] = (__bf16)acc[rt][j][r];
            }
        }
}

// ---- fused recurrence + head ----------------------------------------------
__global__ __launch_bounds__(512, 2) void gru_rec_kernel(
    const __bf16* __restrict__ gi0,
    const __bf16* __restrict__ Whh0, const __bf16* __restrict__ Wih1,
    const __bf16* __restrict__ Whh1,
    const float* __restrict__ b_ih0, const float* __restrict__ b_hh0,
    const float* __restrict__ b_ih1, const float* __restrict__ b_hh1,
    const float* __restrict__ W1, const float* __restrict__ b1,
    const float* __restrict__ W2, const float* __restrict__ b2,
    float* __restrict__ out)
{
    __shared__ __align__(16) __bf16 h0sA[16 * HS], h0sB[16 * HS];
    __shared__ __align__(16) __bf16 h1sA[16 * HS], h1sB[16 * HS];
    __shared__ float h1f[16 * 128];
    __shared__ float hdnf[16 * 64];

    const int tid  = threadIdx.x;
    const int w    = tid >> 6;
    const int lane = tid & 63;
    const int q    = lane >> 4;
    const int c15  = lane & 15;
    const int c_col = w * 16 + c15;   // gate/hidden column this lane owns
    const int b0   = blockIdx.x * 16;

    // --- B-fragments forced into VGPRs via volatile loads (no remat) --------
    bf16x8 fhh0[3][4], fih1[3][4], fhh1[3][4];
    #pragma unroll
    for (int g = 0; g < 3; ++g) {
        int row = g * 128 + c_col;
        #pragma unroll
        for (int ks = 0; ks < 4; ++ks) {
            size_t off = (size_t)row * 128 + ks * 32 + q * 8;
            fhh0[g][ks] = __builtin_bit_cast(bf16x8, *(const volatile u32x4v*)(Whh0 + off));
            fih1[g][ks] = __builtin_bit_cast(bf16x8, *(const volatile u32x4v*)(Wih1 + off));
            fhh1[g][ks] = __builtin_bit_cast(bf16x8, *(const volatile u32x4v*)(Whh1 + off));
        }
    }
    float bi0[3], bh0[3], bi1[3], bh1[3];
    #pragma unroll
    for (int g = 0; g < 3; ++g) {
        bi0[g] = b_ih0[g * 128 + c_col];
        bh0[g] = b_hh0[g * 128 + c_col];
        bi1[g] = b_ih1[g * 128 + c_col];
        bh1[g] = b_hh1[g * 128 + c_col];
    }

    float h0r[4] = {0.f, 0.f, 0.f, 0.f};
    float h1r[4] = {0.f, 0.f, 0.f, 0.f};
    for (int i = tid; i < 16 * HS; i += 512) {
        h0sA[i] = (__bf16)0.f; h0sB[i] = (__bf16)0.f;
        h1sA[i] = (__bf16)0.f; h1sB[i] = (__bf16)0.f;
    }
    __syncthreads();

    // gi0 row pointers: rows (b0+q*4+r), stepping t -> +384 elems
    const __bf16* gp[4];
    #pragma unroll
    for (int r = 0; r < 4; ++r)
        gp[r] = gi0 + (size_t)(b0 + q * 4 + r) * 256 * 384 + c_col;

    // one step; exactly ONE barrier (double-buffered h0/h1)
    auto do_step = [&](const __bf16* h0rd, __bf16* h0wr,
                       const __bf16* h1rd, __bf16* h1wr) {
        // gi0 loads for this step (consumed after gh0 phase -> latency hidden)
        __bf16 giv[4][3];
        #pragma unroll
        for (int r = 0; r < 4; ++r)
            #pragma unroll
            for (int g = 0; g < 3; ++g) giv[r][g] = gp[r][g * 128];

        // gh0 = h0 @ Whh0^T
        f32x4 hacc[3];
        #pragma unroll
        for (int g = 0; g < 3; ++g) hacc[g] = (f32x4){0.f, 0.f, 0.f, 0.f};
        #pragma unroll
        for (int ks = 0; ks < 4; ++ks) {
            bf16x8 a = *(const bf16x8*)(h0rd + c15 * HS + ks * 32 + q * 8);
            #pragma unroll
            for (int g = 0; g < 3; ++g) hacc[g] = mfma16(a, fhh0[g][ks], hacc[g]);
        }
        // layer-0 gates -> h0wr (other buffer: no barrier needed before write)
        #pragma unroll
        for (int r = 0; r < 4; ++r) {
            float rr = sigf((float)giv[r][0] + bi0[0] + hacc[0][r] + bh0[0]);
            float zz = sigf((float)giv[r][1] + bi0[1] + hacc[1][r] + bh0[1]);
            float nn = tanhf_((float)giv[r][2] + bi0[2] + rr * (hacc[2][r] + bh0[2]));
            float hnew = (1.f - zz) * nn + zz * h0r[r];
            h0r[r] = hnew;
            h0wr[(q * 4 + r) * HS + c_col] = (__bf16)hnew;
        }
        __syncthreads();   // the ONLY barrier this step
        // gi1 = h0_new @ Wih1^T ; gh1 = h1 @ Whh1^T
        f32x4 iacc[3], hacc1[3];
        #pragma unroll
        for (int g = 0; g < 3; ++g) {
            iacc[g]  = (f32x4){0.f, 0.f, 0.f, 0.f};
            hacc1[g] = (f32x4){0.f, 0.f, 0.f, 0.f};
        }
        #pragma unroll
        for (int ks = 0; ks < 4; ++ks) {
            bf16x8 a0 = *(const bf16x8*)(h0wr + c15 * HS + ks * 32 + q * 8);
            bf16x8 a1 = *(const bf16x8*)(h1rd + c15 * HS + ks * 32 + q * 8);
            #pragma unroll
            for (int g = 0; g < 3; ++g) {
                iacc[g]  = mfma16(a0, fih1[g][ks], iacc[g]);
                hacc1[g] = mfma16(a1, fhh1[g][ks], hacc1[g]);
            }
        }
        // layer-1 gates -> h1wr (next read of h1wr is after next step's barrier)
        #pragma unroll
        for (int r = 0; r < 4; ++r) {
            float rr = sigf(iacc[0][r] + bi1[0] + hacc1[0][r] + bh1[0]);
            float zz = sigf(iacc[1][r] + bi1[1] + hacc1[1][r] + bh1[1]);
            float nn = tanhf_(iacc[2][r] + bi1[2] + rr * (hacc1[2][r] + bh1[2]));
            float hnew = (1.f - zz) * nn + zz * h1r[r];
            h1r[r] = hnew;
            h1wr[(q * 4 + r) * HS + c_col] = (__bf16)hnew;
        }
        #pragma unroll
        for (int r = 0; r < 4; ++r) gp[r] += 384;
    };

    for (int tt = 0; tt < 128; ++tt) {
        do_step(h0sA, h0sB, h1sA, h1sB);   // even t: read A, write B
        do_step(h0sB, h0sA, h1sB, h1sA);   // odd  t: read B, write A
    }

    // ---- head: relu(h1 @ W1^T + b1) @ W2^T + b2 -> sigmoid ----------------
    #pragma unroll
    for (int r = 0; r < 4; ++r) h1f[(q * 4 + r) * 128 + c_col] = h1r[r];
    __syncthreads();
    for (int p = tid; p < 16 * 64; p += 512) {
        int m = p >> 6, u = p & 63;
        float s = b1[u];
        const float* hrow = &h1f[m * 128];
        const float* wrow = &W1[u * 128];
        #pragma unroll 8
        for (int k = 0; k < 128; ++k) s += hrow[k] * wrow[k];
        hdnf[p] = fmaxf(s, 0.f);
    }
    __syncthreads();
    if (tid < 16) {
        float s = b2[0];
        #pragma unroll 8
        for (int k = 0; k < 64; ++k) s += hdnf[tid * 64 + k] * W2[k];
        out[b0 + tid] = sigf(s);
    }
}

// ---------------------------------------------------------------------------
extern "C" void kernel_launch(void* const* d_in, const int* in_sizes, int n_in,
                              void* d_out, int out_size, void* d_ws, size_t ws_size,
                              hipStream_t stream) {
    const float* x     = (const float*)d_in[0];
    const float* W_ih0 = (const float*)d_in[1];
    const float* W_hh0 = (const float*)d_in[2];
    const float* bih0  = (const float*)d_in[3];
    const float* bhh0  = (const float*)d_in[4];
    const float* W_ih1 = (const float*)d_in[5];
    const float* W_hh1 = (const float*)d_in[6];
    const float* bih1  = (const float*)d_in[7];
    const float* bhh1  = (const float*)d_in[8];
    const float* W1    = (const float*)d_in[9];
    const float* b1    = (const float*)d_in[10];
    const float* W2    = (const float*)d_in[11];
    const float* b2    = (const float*)d_in[12];
    float* out = (float*)d_out;

    char* ws = (char*)d_ws;
    // ws layout (bytes):
    //   gi0   : 262144 x 384 bf16 = 201,326,592   @ 0
    //   Wih0b : 384x160 bf16      =     122,880   @ 201326592
    //   Whh0b / Wih1b / Whh1b : 384x128 bf16 = 98,304 each
    __bf16* gi0   = (__bf16*)(ws);
    __bf16* wih0b = (__bf16*)(ws + 201326592);
    __bf16* whh0b = (__bf16*)(ws + 201449472);
    __bf16* wih1b = (__bf16*)(ws + 201547776);
    __bf16* whh1b = (__bf16*)(ws + 201646080);

    prep_w_kernel<<<240, 256, 0, stream>>>(W_ih0, W_hh0, W_ih1, W_hh1,
                                           wih0b, whh0b, wih1b, whh1b);
    gi0_gemm_kernel<<<2048, 512, 0, stream>>>(x, wih0b, gi0);
    gru_rec_kernel<<<64, 512, 0, stream>>>(gi0, whh0b, wih1b, whh1b,
                                           bih0, bhh0, bih1, bhh1,
                                           W1, b1, W2, b2, out);
}

// Round 3
// 1034.300 us; speedup vs baseline: 1.8249x; 1.8249x over previous
//
#include <hip/hip_runtime.h>

// ---------------------------------------------------------------------------
// TorchGRUClassifier: 2-layer GRU (B=1024, T=256, I=153, H=128) + MLP head.
// Round 3: amdgpu_waves_per_eu(2,2) so the allocator may use 256 VGPRs ->
// the 36 recurrent weight B-fragments become truly register-resident
// (rounds 1/2 showed VGPR_Count=128/124: remat/spill every step).
// Plus: gi0 values prefetched one full step ahead; gi0_gemm epilogue made
// coalesced via an LDS round-trip.
// ---------------------------------------------------------------------------

typedef __bf16 bf16x8 __attribute__((ext_vector_type(8)));
typedef float  f32x4  __attribute__((ext_vector_type(4)));

#define HS 136   // LDS row stride (bf16) for h tiles: 272 B -> uniform banks
#define OS 136   // LDS row stride (bf16) for gi0 output tile (16B-aligned rows)

__device__ __forceinline__ f32x4 mfma16(bf16x8 a, bf16x8 b, f32x4 c) {
    return __builtin_amdgcn_mfma_f32_16x16x32_bf16(a, b, c, 0, 0, 0);
}
__device__ __forceinline__ float sigf(float x)   { return 1.f / (1.f + __expf(-x)); }
__device__ __forceinline__ float tanhf_(float x) { return 2.f * sigf(2.f * x) - 1.f; }

// ---- prep: cast weights to bf16 (W_ih0 padded K 153->160 with zeros) ------
__global__ void prep_w_kernel(const float* __restrict__ Wih0, const float* __restrict__ Whh0,
                              const float* __restrict__ Wih1, const float* __restrict__ Whh1,
                              __bf16* __restrict__ o_ih0, __bf16* __restrict__ o_hh0,
                              __bf16* __restrict__ o_ih1, __bf16* __restrict__ o_hh1) {
    int idx = blockIdx.x * 256 + threadIdx.x;      // grid covers 384*160 = 61440
    if (idx < 384 * 160) {
        int n = idx / 160, k = idx - n * 160;
        o_ih0[idx] = (__bf16)(k < 153 ? Wih0[n * 153 + k] : 0.f);
    }
    if (idx < 384 * 128) {
        o_hh0[idx] = (__bf16)Whh0[idx];
        o_ih1[idx] = (__bf16)Wih1[idx];
        o_hh1[idx] = (__bf16)Whh1[idx];
    }
}

// ---- gi0 GEMM: [262144,153(pad160)] x [160,384] -> gi0 bf16 [262144][384] --
// row = b*256 + t. Casts x f32->bf16 during LDS staging; epilogue goes
// through LDS so global stores are 16B coalesced.
__global__ __launch_bounds__(512, 2) void gi0_gemm_kernel(
    const float* __restrict__ x, const __bf16* __restrict__ Wih0b,
    __bf16* __restrict__ gi0)
{
    __shared__ __align__(16) __bf16 smem[128 * 160];   // As (80KB), reused as Os
    const int r0  = blockIdx.x * 128;
    const int tid = threadIdx.x;
    for (int e = tid; e < 128 * 160; e += 512) {
        int r = e / 160, c = e - r * 160;
        float v = (c < 153) ? x[(size_t)(r0 + r) * 153 + c] : 0.f;
        smem[e] = (__bf16)v;
    }
    __syncthreads();
    const int w = tid >> 6, lane = tid & 63, q = lane >> 4, c15 = lane & 15;

    bf16x8 bf[3][5];
    #pragma unroll
    for (int j = 0; j < 3; ++j) {
        int colb = 16 * (w + 8 * j) + c15;
        #pragma unroll
        for (int ks = 0; ks < 5; ++ks)
            bf[j][ks] = *(const bf16x8*)(Wih0b + colb * 160 + ks * 32 + q * 8);
    }
    f32x4 acc[8][3];
    #pragma unroll
    for (int rt = 0; rt < 8; ++rt)
        #pragma unroll
        for (int j = 0; j < 3; ++j) acc[rt][j] = (f32x4){0.f, 0.f, 0.f, 0.f};

    #pragma unroll
    for (int ks = 0; ks < 5; ++ks) {
        bf16x8 a[8];
        #pragma unroll
        for (int rt = 0; rt < 8; ++rt)
            a[rt] = *(const bf16x8*)(&smem[(rt * 16 + c15) * 160 + ks * 32 + q * 8]);
        #pragma unroll
        for (int rt = 0; rt < 8; ++rt)
            #pragma unroll
            for (int j = 0; j < 3; ++j) acc[rt][j] = mfma16(a[rt], bf[j][ks], acc[rt][j]);
    }
    __syncthreads();   // done reading As; reuse as Os
    // chunk j covers contiguous output cols [128j, 128j+128)
    #pragma unroll
    for (int j = 0; j < 3; ++j) {
        #pragma unroll
        for (int rt = 0; rt < 8; ++rt)
            #pragma unroll
            for (int r = 0; r < 4; ++r)
                smem[(rt * 16 + q * 4 + r) * OS + 16 * w + c15] = (__bf16)acc[rt][j][r];
        __syncthreads();
        // coalesced stores: 16 lanes x 16B = one 256B row segment
        #pragma unroll
        for (int pass = 0; pass < 4; ++pass) {
            int row = pass * 32 + (tid >> 4);
            int col = (tid & 15) * 8;
            bf16x8 v = *(const bf16x8*)(&smem[row * OS + col]);
            *(bf16x8*)(gi0 + (size_t)(r0 + row) * 384 + j * 128 + col) = v;
        }
        if (j < 2) __syncthreads();
    }
}

// ---- fused recurrence + head ----------------------------------------------
__global__ __attribute__((amdgpu_flat_work_group_size(512, 512)))
__attribute__((amdgpu_waves_per_eu(2, 2)))
void gru_rec_kernel(
    const __bf16* __restrict__ gi0,
    const __bf16* __restrict__ Whh0, const __bf16* __restrict__ Wih1,
    const __bf16* __restrict__ Whh1,
    const float* __restrict__ b_ih0, const float* __restrict__ b_hh0,
    const float* __restrict__ b_ih1, const float* __restrict__ b_hh1,
    const float* __restrict__ W1, const float* __restrict__ b1,
    const float* __restrict__ W2, const float* __restrict__ b2,
    float* __restrict__ out)
{
    __shared__ __align__(16) __bf16 h0sA[16 * HS], h0sB[16 * HS];
    __shared__ __align__(16) __bf16 h1sA[16 * HS], h1sB[16 * HS];
    __shared__ float h1f[16 * 128];
    __shared__ float hdnf[16 * 64];

    const int tid  = threadIdx.x;
    const int w    = tid >> 6;
    const int lane = tid & 63;
    const int q    = lane >> 4;
    const int c15  = lane & 15;
    const int c_col = w * 16 + c15;   // gate/hidden column this lane owns
    const int b0   = blockIdx.x * 16;

    // --- weight B-fragments, register-resident (36 frags = 144 VGPRs) ------
    bf16x8 fhh0[3][4], fih1[3][4], fhh1[3][4];
    #pragma unroll
    for (int g = 0; g < 3; ++g) {
        int row = g * 128 + c_col;
        #pragma unroll
        for (int ks = 0; ks < 4; ++ks) {
            size_t off = (size_t)row * 128 + ks * 32 + q * 8;
            fhh0[g][ks] = *(const bf16x8*)(Whh0 + off);
            fih1[g][ks] = *(const bf16x8*)(Wih1 + off);
            fhh1[g][ks] = *(const bf16x8*)(Whh1 + off);
        }
    }
    // biases: r,z gates use (b_ih + b_hh) combined; n gate keeps them split
    float B0rz[2], B1rz[2], bi0n, bh0n, bi1n, bh1n;
    B0rz[0] = b_ih0[c_col] + b_hh0[c_col];
    B0rz[1] = b_ih0[128 + c_col] + b_hh0[128 + c_col];
    B1rz[0] = b_ih1[c_col] + b_hh1[c_col];
    B1rz[1] = b_ih1[128 + c_col] + b_hh1[128 + c_col];
    bi0n = b_ih0[256 + c_col]; bh0n = b_hh0[256 + c_col];
    bi1n = b_ih1[256 + c_col]; bh1n = b_hh1[256 + c_col];

    float h0r[4] = {0.f, 0.f, 0.f, 0.f};
    float h1r[4] = {0.f, 0.f, 0.f, 0.f};
    for (int i = tid; i < 16 * HS; i += 512) {
        h0sA[i] = (__bf16)0.f; h0sB[i] = (__bf16)0.f;
        h1sA[i] = (__bf16)0.f; h1sB[i] = (__bf16)0.f;
    }
    __syncthreads();

    // gi0 row pointers: rows (b0+q*4+r), stepping t -> +384 elems
    const __bf16* gp[4];
    #pragma unroll
    for (int r = 0; r < 4; ++r)
        gp[r] = gi0 + (size_t)(b0 + q * 4 + r) * 256 * 384 + c_col;

    // gi0 software pipeline: givC = current step, prefetched one step ahead
    __bf16 givC[4][3];
    #pragma unroll
    for (int r = 0; r < 4; ++r)
        #pragma unroll
        for (int g = 0; g < 3; ++g) givC[r][g] = gp[r][g * 128];
    #pragma unroll
    for (int r = 0; r < 4; ++r) gp[r] += 384;

    // one step; ONE barrier (double-buffered h0/h1)
    auto do_step = [&](const __bf16* h0rd, __bf16* h0wr,
                       const __bf16* h1rd, __bf16* h1wr, bool last) {
        // prefetch NEXT step's gi0 (consumed next step -> full-step latency)
        __bf16 givN[4][3];
        if (!last) {
            #pragma unroll
            for (int r = 0; r < 4; ++r)
                #pragma unroll
                for (int g = 0; g < 3; ++g) givN[r][g] = gp[r][g * 128];
            #pragma unroll
            for (int r = 0; r < 4; ++r) gp[r] += 384;
        }

        // gh0 = h0 @ Whh0^T
        f32x4 hacc[3];
        #pragma unroll
        for (int g = 0; g < 3; ++g) hacc[g] = (f32x4){0.f, 0.f, 0.f, 0.f};
        #pragma unroll
        for (int ks = 0; ks < 4; ++ks) {
            bf16x8 a = *(const bf16x8*)(h0rd + c15 * HS + ks * 32 + q * 8);
            #pragma unroll
            for (int g = 0; g < 3; ++g) hacc[g] = mfma16(a, fhh0[g][ks], hacc[g]);
        }
        // layer-0 gates -> h0wr (other buffer; separated from reads by prev barrier)
        #pragma unroll
        for (int r = 0; r < 4; ++r) {
            float rr = sigf((float)givC[r][0] + hacc[0][r] + B0rz[0]);
            float zz = sigf((float)givC[r][1] + hacc[1][r] + B0rz[1]);
            float nn = tanhf_((float)givC[r][2] + bi0n + rr * (hacc[2][r] + bh0n));
            float hnew = zz * (h0r[r] - nn) + nn;
            h0r[r] = hnew;
            h0wr[(q * 4 + r) * HS + c_col] = (__bf16)hnew;
        }
        __syncthreads();   // the ONLY barrier this step
        // gi1 = h0_new @ Wih1^T ; gh1 = h1 @ Whh1^T
        f32x4 iacc[3], hacc1[3];
        #pragma unroll
        for (int g = 0; g < 3; ++g) {
            iacc[g]  = (f32x4){0.f, 0.f, 0.f, 0.f};
            hacc1[g] = (f32x4){0.f, 0.f, 0.f, 0.f};
        }
        #pragma unroll
        for (int ks = 0; ks < 4; ++ks) {
            bf16x8 a0 = *(const bf16x8*)(h0wr + c15 * HS + ks * 32 + q * 8);
            bf16x8 a1 = *(const bf16x8*)(h1rd + c15 * HS + ks * 32 + q * 8);
            #pragma unroll
            for (int g = 0; g < 3; ++g) {
                iacc[g]  = mfma16(a0, fih1[g][ks], iacc[g]);
                hacc1[g] = mfma16(a1, fhh1[g][ks], hacc1[g]);
            }
        }
        // layer-1 gates -> h1wr (next read is after next step's barrier)
        #pragma unroll
        for (int r = 0; r < 4; ++r) {
            float rr = sigf(iacc[0][r] + hacc1[0][r] + B1rz[0]);
            float zz = sigf(iacc[1][r] + hacc1[1][r] + B1rz[1]);
            float nn = tanhf_(iacc[2][r] + bi1n + rr * (hacc1[2][r] + bh1n));
            float hnew = zz * (h1r[r] - nn) + nn;
            h1r[r] = hnew;
            h1wr[(q * 4 + r) * HS + c_col] = (__bf16)hnew;
        }
        // rotate gi pipeline
        #pragma unroll
        for (int r = 0; r < 4; ++r)
            #pragma unroll
            for (int g = 0; g < 3; ++g) givC[r][g] = givN[r][g];
    };

    for (int tt = 0; tt < 128; ++tt) {
        do_step(h0sA, h0sB, h1sA, h1sB, false);       // even t
        do_step(h0sB, h0sA, h1sB, h1sA, tt == 127);   // odd  t
    }

    // ---- head: relu(h1 @ W1^T + b1) @ W2^T + b2 -> sigmoid ----------------
    #pragma unroll
    for (int r = 0; r < 4; ++r) h1f[(q * 4 + r) * 128 + c_col] = h1r[r];
    __syncthreads();
    for (int p = tid; p < 16 * 64; p += 512) {
        int m = p >> 6, u = p & 63;
        float s = b1[u];
        const float* hrow = &h1f[m * 128];
        const float* wrow = &W1[u * 128];
        #pragma unroll 8
        for (int k = 0; k < 128; ++k) s += hrow[k] * wrow[k];
        hdnf[p] = fmaxf(s, 0.f);
    }
    __syncthreads();
    if (tid < 16) {
        float s = b2[0];
        #pragma unroll 8
        for (int k = 0; k < 64; ++k) s += hdnf[tid * 64 + k] * W2[k];
        out[b0 + tid] = sigf(s);
    }
}

// ---------------------------------------------------------------------------
extern "C" void kernel_launch(void* const* d_in, const int* in_sizes, int n_in,
                              void* d_out, int out_size, void* d_ws, size_t ws_size,
                              hipStream_t stream) {
    const float* x     = (const float*)d_in[0];
    const float* W_ih0 = (const float*)d_in[1];
    const float* W_hh0 = (const float*)d_in[2];
    const float* bih0  = (const float*)d_in[3];
    const float* bhh0  = (const float*)d_in[4];
    const float* W_ih1 = (const float*)d_in[5];
    const float* W_hh1 = (const float*)d_in[6];
    const float* bih1  = (const float*)d_in[7];
    const float* bhh1  = (const float*)d_in[8];
    const float* W1    = (const float*)d_in[9];
    const float* b1    = (const float*)d_in[10];
    const float* W2    = (const float*)d_in[11];
    const float* b2    = (const float*)d_in[12];
    float* out = (float*)d_out;

    char* ws = (char*)d_ws;
    // ws layout (bytes):
    //   gi0   : 262144 x 384 bf16 = 201,326,592   @ 0
    //   Wih0b : 384x160 bf16      =     122,880   @ 201326592
    //   Whh0b / Wih1b / Whh1b : 384x128 bf16 = 98,304 each
    __bf16* gi0   = (__bf16*)(ws);
    __bf16* wih0b = (__bf16*)(ws + 201326592);
    __bf16* whh0b = (__bf16*)(ws + 201449472);
    __bf16* wih1b = (__bf16*)(ws + 201547776);
    __bf16* whh1b = (__bf16*)(ws + 201646080);

    prep_w_kernel<<<240, 256, 0, stream>>>(W_ih0, W_hh0, W_ih1, W_hh1,
                                           wih0b, whh0b, wih1b, whh1b);
    gi0_gemm_kernel<<<2048, 512, 0, stream>>>(x, wih0b, gi0);
    gru_rec_kernel<<<64, 512, 0, stream>>>(gi0, whh0b, wih1b, whh1b,
                                           bih0, bhh0, bih1, bhh1,
                                           W1, b1, W2, b2, out);
}